// Round 4
// baseline (886.838 us; speedup 1.0000x reference)
//
#include <hip/hip_runtime.h>
#include <hip/hip_bf16.h>

#define N_EXP   8
#define NTOK    2048   // B*S
#define TOTROWS 4096   // NTOK * TOP_K
#define PTOK    4      // tokens per policy block

typedef __hip_bfloat16 bf16;
typedef __attribute__((ext_vector_type(8))) short short8;   // 8 bf16 (4 VGPRs)
typedef __attribute__((ext_vector_type(4))) float floatx4;  // MFMA acc

#define TN 128
#define TK 32
#define LDAB 40   // padded bf16 row stride for LDS tiles (80B: 16B-aligned, 2-way max)

// ---------------- helpers ----------------

__device__ inline float gelu_f(float v) {
    return 0.5f * v * (1.0f + erff(v * 0.70710678118654752440f));
}

__device__ inline float block_sum256(float v, float* red) {
    #pragma unroll
    for (int off = 32; off > 0; off >>= 1)
        v += __shfl_down(v, off, 64);
    __syncthreads();
    if ((threadIdx.x & 63) == 0) red[threadIdx.x >> 6] = v;
    __syncthreads();
    return red[0] + red[1] + red[2] + red[3];
}

__device__ inline unsigned rotl32(unsigned v, int d) { return (v << d) | (v >> (32 - d)); }

// JAX threefry2x32, key = (k0,k1)
__device__ inline void threefry2x32(unsigned k0, unsigned k1, unsigned x0, unsigned x1,
                                    unsigned& o0, unsigned& o1) {
    unsigned ks2 = k0 ^ k1 ^ 0x1BD11BDAu;
    x0 += k0; x1 += k1;
#define TF_R(r) { x0 += x1; x1 = rotl32(x1, r); x1 ^= x0; }
    TF_R(13) TF_R(15) TF_R(26) TF_R(6)
    x0 += k1; x1 += ks2 + 1u;
    TF_R(17) TF_R(29) TF_R(16) TF_R(24)
    x0 += ks2; x1 += k0 + 2u;
    TF_R(13) TF_R(15) TF_R(26) TF_R(6)
    x0 += k0; x1 += k1 + 3u;
    TF_R(17) TF_R(29) TF_R(16) TF_R(24)
    x0 += k1; x1 += ks2 + 4u;
    TF_R(13) TF_R(15) TF_R(26) TF_R(6)
    x0 += ks2; x1 += k0 + 5u;
#undef TF_R
    o0 = x0; o1 = x1;
}

__device__ inline int expert_of(int r, const int* bases) {
    int e = 0;
    #pragma unroll
    for (int i = 1; i < N_EXP; ++i) if (r >= bases[i]) e = i;
    return e;
}

// ---------------- policy + routing ----------------
// 4 tokens/block: pw1 column load reused 4x, 4 independent fma chains.

__global__ __launch_bounds__(256) void policy_k(
    const float* __restrict__ x, const float* __restrict__ pw1,
    const float* __restrict__ pb1, const float* __restrict__ pg1,
    const float* __restrict__ pbb1, const float* __restrict__ pw2,
    const float* __restrict__ pb2, int2* __restrict__ top2, int* __restrict__ counts)
{
    const int tb  = blockIdx.x * PTOK;
    const int lid = threadIdx.x;
    __shared__ float xs[PTOK][512];
    __shared__ float hbs[PTOK][256];
    __shared__ float red[4];
    __shared__ float sc[PTOK][8];

    {
        const float4* xp = (const float4*)(x + (long long)tb * 512);
        float4* xsp = (float4*)&xs[0][0];
        xsp[lid]       = xp[lid];
        xsp[lid + 256] = xp[lid + 256];
    }
    __syncthreads();

    float av[PTOK];
    {
        float b0 = pb1[lid];
        #pragma unroll
        for (int tt = 0; tt < PTOK; ++tt) av[tt] = b0;
    }
    #pragma unroll 4
    for (int d = 0; d < 512; ++d) {
        float w = pw1[d * 256 + lid];
        #pragma unroll
        for (int tt = 0; tt < PTOK; ++tt)
            av[tt] = fmaf(xs[tt][d], w, av[tt]);
    }

    #pragma unroll
    for (int tt = 0; tt < PTOK; ++tt) {
        float s  = block_sum256(av[tt], red);
        float sq = block_sum256(av[tt] * av[tt], red);
        float mean = s * (1.0f / 256.0f);
        float var  = sq * (1.0f / 256.0f) - mean * mean;
        float rstd = rsqrtf(var + 1e-5f);
        float hn = (av[tt] - mean) * rstd * pg1[lid] + pbb1[lid];
        hbs[tt][lid] = gelu_f(hn);
    }
    __syncthreads();

    if (lid < PTOK * 8) {
        const int tt = lid >> 3;
        const int e  = lid & 7;
        float lg = pb2[e];
        for (int j = 0; j < 256; ++j)
            lg = fmaf(hbs[tt][j], pw2[j * 8 + e], lg);
        // jax_threefry_partitionable path: bits = o0 ^ o1 of tf(key, 0, i)
        unsigned idx = (unsigned)(tb + tt) * 8u + (unsigned)e;
        unsigned o0, o1;
        threefry2x32(0u, 42u, 0u, idx, o0, o1);
        unsigned bits = o0 ^ o1;
        float u = __uint_as_float((bits >> 9) | 0x3f800000u) - 1.0f;
        float gml = -logf(-logf(u + 1e-10f) + 1e-10f);
        sc[tt][e] = lg + gml;   // TEMP = 1
    }
    __syncthreads();
    if (lid < PTOK) {
        float b0 = -INFINITY; int i0 = 0;
        #pragma unroll
        for (int e = 0; e < 8; ++e) if (sc[lid][e] > b0) { b0 = sc[lid][e]; i0 = e; }
        float b1v = -INFINITY; int i1 = 0;
        #pragma unroll
        for (int e = 0; e < 8; ++e) if (e != i0 && sc[lid][e] > b1v) { b1v = sc[lid][e]; i1 = e; }
        top2[tb + lid] = make_int2(i0, i1);
        atomicAdd(&counts[i0], 1);
        atomicAdd(&counts[i1], 1);
    }
}

__global__ void prefix_k(const int* __restrict__ counts, int* __restrict__ cursor,
                         int* __restrict__ bases) {
    if (threadIdx.x == 0 && blockIdx.x == 0) {
        int s = 0;
        for (int e = 0; e < N_EXP; ++e) { bases[e] = s; cursor[e] = s; s += counts[e]; }
    }
}

__global__ __launch_bounds__(256) void scatter_k(const int2* __restrict__ top2,
                                                 int* __restrict__ cursor,
                                                 int* __restrict__ list) {
    int t = blockIdx.x * 256 + threadIdx.x;
    int2 p = top2[t];
    int pos = atomicAdd(&cursor[p.x], 1); list[pos] = t;
    pos     = atomicAdd(&cursor[p.y], 1); list[pos] = t;
}

// ---------------- x -> bf16 cast ----------------

__global__ __launch_bounds__(256) void cast_x_k(const float* __restrict__ x,
                                                bf16* __restrict__ xb) {
    int i = (blockIdx.x * 256 + threadIdx.x) * 4;
    float4 v = *(const float4*)(x + i);
    bf16 o[4] = { (bf16)v.x, (bf16)v.y, (bf16)v.z, (bf16)v.w };
    *(unsigned long long*)(xb + i) = *(unsigned long long*)o;
}

// ---------------- weight transpose-cast: [B][R][C] fp32 -> [B][C][R] bf16 ----------------
// 64x64 tiles via LDS; coalesced float4 reads, coalesced 32B bf16 writes.

__global__ __launch_bounds__(256) void wcast_k(const float* __restrict__ in,
                                               bf16* __restrict__ outp,
                                               int R, int C, int tiles_r)
{
    const int mt = blockIdx.x;
    const long long b = blockIdx.y;
    const int tr = mt % tiles_r;
    const int tc = mt / tiles_r;
    const int r0 = tr * 64, c0 = tc * 64;
    __shared__ unsigned short t[64 * 80];   // [c][r], stride 80 (160B, 16B-aligned)
    const int tid = threadIdx.x;
    const int rr = tid >> 4;          // 0..15
    const int cc = (tid & 15) * 4;    // 0..60
    const float* inb = in + ((long long)b * R + r0) * (long long)C + c0;
    #pragma unroll
    for (int i = 0; i < 4; ++i) {
        int r = rr + 16 * i;
        float4 v = *(const float4*)(inb + (long long)r * C + cc);
        bf16 x0 = (bf16)v.x, x1 = (bf16)v.y, x2 = (bf16)v.z, x3 = (bf16)v.w;
        t[(cc + 0) * 80 + r] = *(unsigned short*)&x0;
        t[(cc + 1) * 80 + r] = *(unsigned short*)&x1;
        t[(cc + 2) * 80 + r] = *(unsigned short*)&x2;
        t[(cc + 3) * 80 + r] = *(unsigned short*)&x3;
    }
    __syncthreads();
    const int cr = tid >> 2;          // 0..63
    const int rk = (tid & 3) * 16;    // 0,16,32,48
    bf16* ob = outp + ((long long)b * C + c0 + cr) * (long long)R + r0 + rk;
    uint4 w0 = *(const uint4*)(&t[cr * 80 + rk]);
    uint4 w1 = *(const uint4*)(&t[cr * 80 + rk + 8]);
    *(uint4*)(ob)     = w0;
    *(uint4*)(ob + 8) = w1;
}

// ---------------- MFMA grouped GEMM (pipelined) ----------------
// C[rbase+m][n] = act(A[row][k] * W_e[k][n] + bias_e[n]); A bf16.
// BT=true: weights pre-transposed bf16 [N][K] -> B staging is 2 uint4 loads +
//   2 ds_write_b128 per thread per K-step (no cvt, no strided fp32 loads).
// BT=false: fallback, fp32 [K][N] weights converted in-flight.
// Software pipeline: LDS double-buffer, register prefetch distance 2 K-tiles,
// ONE barrier per K-step.

template <typename CT, int TMp, bool BT>
__global__ __launch_bounds__(256) void mgemm_k(
    const bf16* __restrict__ A, const int* __restrict__ gather,
    const float* __restrict__ W, const bf16* __restrict__ WT, long long westride,
    const float* __restrict__ bias, int bestride,
    CT* __restrict__ C, bf16* __restrict__ Cmir,
    const int* __restrict__ counts, const int* __restrict__ bases,
    int K, int N, int act)
{
    const int e   = blockIdx.z;
    const int cnt = counts[e];
    const int m0  = blockIdx.y * TMp;
    if (m0 >= cnt) return;
    const int rbase = bases[e];
    const int n0  = blockIdx.x * TN;

    constexpr int MI = TMp / 32;   // per-wave 16-row fragment count

    __shared__ __align__(16) unsigned short As[2][TMp * LDAB];  // [m][k] bf16 bits
    __shared__ __align__(16) unsigned short Bs[2][TN * LDAB];   // [n][k] bf16 bits

    const int tid  = threadIdx.x;
    const int lane = tid & 63;
    const int wv   = tid >> 6;
    const int wm   = (wv & 1) * (TMp / 2);
    const int wn   = (wv >> 1) * 64;
    const int q    = lane >> 4;
    const int ln   = lane & 15;

    // A staging coords: thread loads 8 bf16 (16B); 64 rows per round.
    const int ar = tid >> 2;
    const int ak = (tid & 3) * 8;
    long long arow0 = 0, arow1 = 0;
    {
        int r0 = m0 + ar; if (r0 > cnt - 1) r0 = cnt - 1;
        long long p0 = gather ? (long long)gather[rbase + r0] : (long long)(rbase + r0);
        arow0 = p0 * K;
        if (TMp == 128) {
            int r1 = m0 + 64 + ar; if (r1 > cnt - 1) r1 = cnt - 1;
            long long p1 = gather ? (long long)gather[rbase + r1] : (long long)(rbase + r1);
            arow1 = p1 * K;
        }
    }
    // B staging coords: thread owns one n column, 16 consecutive k values.
    const int bn  = (wv & 1) * 64 + lane;   // n within tile, 0..127
    const int bkb = (wv >> 1) * 16;         // k sub-base: 0 or 16
    const float* wcol = BT ? nullptr : (W + (long long)e * westride + n0 + bn);
    const bf16*  wtcol = BT ? (WT + (long long)e * westride
                               + (long long)(n0 + bn) * K + bkb) : nullptr;

    floatx4 acc[MI][4];
    #pragma unroll
    for (int i = 0; i < MI; ++i)
        #pragma unroll
        for (int j = 0; j < 4; ++j)
            acc[i][j] = (floatx4){0.f, 0.f, 0.f, 0.f};

    // two named prefetch register sets (no runtime-indexed reg arrays)
    uint4 aA0 = {0,0,0,0}, aA1 = {0,0,0,0}, aB0 = {0,0,0,0}, aB1 = {0,0,0,0};
    uint4 bA0 = {0,0,0,0}, bA1 = {0,0,0,0}, bB0 = {0,0,0,0}, bB1 = {0,0,0,0};
    float wA[16], wB[16];

    auto mg_load = [&](uint4& a0r, uint4& a1r, uint4& b0r, uint4& b1r,
                       float (&wr)[16], int koff) {
        a0r = *(const uint4*)(A + arow0 + koff + ak);
        if (TMp == 128) a1r = *(const uint4*)(A + arow1 + koff + ak);
        if constexpr (BT) {
            b0r = *(const uint4*)(wtcol + koff);
            b1r = *(const uint4*)(wtcol + koff + 8);
        } else {
            const float* wp = wcol + (long long)(koff + bkb) * N;
            #pragma unroll
            for (int kk = 0; kk < 16; ++kk) wr[kk] = wp[(long long)kk * N];
        }
    };
    auto mg_store = [&](const uint4& a0r, const uint4& a1r, const uint4& b0r,
                        const uint4& b1r, const float (&wr)[16], int buf) {
        *(uint4*)(&As[buf][ar * LDAB + ak]) = a0r;
        if (TMp == 128) *(uint4*)(&As[buf][(64 + ar) * LDAB + ak]) = a1r;
        if constexpr (BT) {
            *(uint4*)(&Bs[buf][bn * LDAB + bkb])     = b0r;
            *(uint4*)(&Bs[buf][bn * LDAB + bkb + 8]) = b1r;
        } else {
            union { unsigned short us[8]; uint4 v; } p0, p1;
            #pragma unroll
            for (int kk = 0; kk < 8; ++kk) {
                bf16 c0 = (bf16)wr[kk];
                bf16 c1 = (bf16)wr[kk + 8];
                p0.us[kk] = *(unsigned short*)&c0;
                p1.us[kk] = *(unsigned short*)&c1;
            }
            *(uint4*)(&Bs[buf][bn * LDAB + bkb])     = p0.v;
            *(uint4*)(&Bs[buf][bn * LDAB + bkb + 8]) = p1.v;
        }
    };
    auto mg_compute = [&](int buf) {
        short8 a_frag[MI], b_frag[4];
        #pragma unroll
        for (int i = 0; i < MI; ++i)
            a_frag[i] = *(const short8*)(&As[buf][(wm + i * 16 + ln) * LDAB + q * 8]);
        #pragma unroll
        for (int j = 0; j < 4; ++j)
            b_frag[j] = *(const short8*)(&Bs[buf][(wn + j * 16 + ln) * LDAB + q * 8]);
        #pragma unroll
        for (int i = 0; i < MI; ++i)
            #pragma unroll
            for (int j = 0; j < 4; ++j)
                acc[i][j] = __builtin_amdgcn_mfma_f32_16x16x32_bf16(
                    a_frag[i], b_frag[j], acc[i][j], 0, 0, 0);
    };

    // prologue: tile 0 -> LDS buf0, tile 1 -> regs B
    mg_load(aA0, aA1, bA0, bA1, wA, 0);
    mg_store(aA0, aA1, bA0, bA1, wA, 0);
    mg_load(aB0, aB1, bB0, bB1, wB, TK);
    __syncthreads();

    // main loop: K is a multiple of 64 (512/1024/2048)
    int k0 = 0;
    for (; k0 + 2 * TK < K; k0 += 2 * TK) {
        mg_load(aA0, aA1, bA0, bA1, wA, k0 + 2 * TK);   // prefetch k+2
        mg_compute(0);                                  // consume tile k0
        mg_store(aB0, aB1, bB0, bB1, wB, 1);            // write tile k0+1
        __syncthreads();
        mg_load(aB0, aB1, bB0, bB1, wB, k0 + 3 * TK);   // prefetch k+3
        mg_compute(1);                                  // consume tile k0+1
        mg_store(aA0, aA1, bA0, bA1, wA, 0);            // write tile k0+2
        __syncthreads();
    }
    // epilogue: k0 == K-64; buf0 holds tile K-64, regs B hold tile K-32
    mg_compute(0);
    mg_store(aB0, aB1, bB0, bB1, wB, 1);
    __syncthreads();
    mg_compute(1);

    // epilogue: C/D layout col = lane&15, row = quad*4 + reg
    #pragma unroll
    for (int i = 0; i < MI; ++i) {
        int rbase_i = m0 + wm + i * 16 + q * 4;
        #pragma unroll
        for (int j = 0; j < 4; ++j) {
            int n = n0 + wn + j * 16 + ln;
            float bv = bias[e * bestride + n];
            #pragma unroll
            for (int rg = 0; rg < 4; ++rg) {
                int r = rbase_i + rg;
                if (r >= cnt) continue;
                float v = acc[i][j][rg] + bv;
                if (act) v = gelu_f(v);
                long long off = (long long)(rbase + r) * N + n;
                C[off] = (CT)v;
                if (Cmir) Cmir[off] = (bf16)v;
            }
        }
    }
}

// ---------------- LN + gate + residual (row-global), writes h fp32 + hb bf16 ----------------

__global__ __launch_bounds__(256) void lngate_k(
    float* __restrict__ h, bf16* __restrict__ hb, const float* __restrict__ h2,
    const float* __restrict__ ng, const float* __restrict__ nb,
    const float* __restrict__ gw, const int* __restrict__ bases, int l)
{
    const int r = blockIdx.x;
    const int e = expert_of(r, bases);
    const int lid = threadIdx.x;
    const float* hr  = h  + (long long)r * 1024;
    const float* h2r = h2 + (long long)r * 1024;
    const int off = (e * 2 + l) * 1024;
    __shared__ float red[4];

    float s = 0.f, sq = 0.f, dt = 0.f;
    float hv[4], h2v[4];
    #pragma unroll
    for (int i = 0; i < 4; ++i) {
        int j = lid + 256 * i;
        float a = h2r[j];
        float b = hr[j];
        hv[i] = b; h2v[i] = a;
        s += a; sq += a * a;
        dt = fmaf(b, gw[off + j], dt);
    }
    s  = block_sum256(s, red);
    sq = block_sum256(sq, red);
    dt = block_sum256(dt, red);
    float mean = s * (1.f / 1024.f);
    float rstd = rsqrtf(sq * (1.f / 1024.f) - mean * mean + 1e-5f);
    float gate = 1.f / (1.f + expf(-dt));
    float* hw  = h  + (long long)r * 1024;
    bf16*  hbw = hb + (long long)r * 1024;
    #pragma unroll
    for (int i = 0; i < 4; ++i) {
        int j = lid + 256 * i;
        float v = (h2v[i] - mean) * rstd * ng[off + j] + nb[off + j];
        float nh = hv[i] + gate * v;
        hw[j] = nh;
        hbw[j] = (bf16)nh;
    }
}

// ---------------- final LN(x + out) + combine ----------------

__global__ __launch_bounds__(256) void final_k(
    const float* __restrict__ x, const bf16* __restrict__ orow,
    const float* __restrict__ fng, const float* __restrict__ fnb,
    const int* __restrict__ bases, const int* __restrict__ list,
    float* __restrict__ out)
{
    const int r = blockIdx.x;
    const int e = expert_of(r, bases);
    const int t = list[r];
    const int lid = threadIdx.x;
    __shared__ float red[4];

    float y[2];
    float s = 0.f, sq = 0.f;
    #pragma unroll
    for (int i = 0; i < 2; ++i) {
        int j = lid + 256 * i;
        float v = x[(long long)t * 512 + j] + (float)orow[(long long)r * 512 + j];
        y[i] = v; s += v; sq += v * v;
    }
    s  = block_sum256(s, red);
    sq = block_sum256(sq, red);
    float mean = s * (1.f / 512.f);
    float rstd = rsqrtf(sq * (1.f / 512.f) - mean * mean + 1e-5f);
    #pragma unroll
    for (int i = 0; i < 2; ++i) {
        int j = lid + 256 * i;
        float v = (y[i] - mean) * rstd * fng[e * 512 + j] + fnb[e * 512 + j];
        atomicAdd(&out[(long long)t * 512 + j], v);
    }
}

// ---------------- launch ----------------

extern "C" void kernel_launch(void* const* d_in, const int* in_sizes, int n_in,
                              void* d_out, int out_size, void* d_ws, size_t ws_size,
                              hipStream_t stream) {
    const float* x    = (const float*)d_in[0];
    const float* pw1  = (const float*)d_in[1];
    const float* pb1  = (const float*)d_in[2];
    const float* pg1  = (const float*)d_in[3];
    const float* pbb1 = (const float*)d_in[4];
    const float* pw2  = (const float*)d_in[5];
    const float* pb2  = (const float*)d_in[6];
    const float* Win  = (const float*)d_in[7];
    const float* b_in = (const float*)d_in[8];
    const float* W1   = (const float*)d_in[9];
    const float* b1   = (const float*)d_in[10];
    const float* W2   = (const float*)d_in[11];
    const float* b2   = (const float*)d_in[12];
    const float* ng   = (const float*)d_in[13];
    const float* nb   = (const float*)d_in[14];
    const float* gw   = (const float*)d_in[15];
    const float* Wout = (const float*)d_in[16];
    const float* bout = (const float*)d_in[17];
    const float* fng  = (const float*)d_in[18];
    const float* fnb  = (const float*)d_in[19];
    float* out = (float*)d_out;
    (void)ws_size; (void)in_sizes; (void)n_in;

    char* ws = (char*)d_ws;
    int* counts = (int*)ws;        // 8 ints @ 0
    int* cursor = counts + 8;      // 8 ints @ 32
    int* bases  = cursor + 8;      // 8 ints @ 64
    int2* top2  = (int2*)(ws + 128);             // 16 KB
    int*  list  = (int*)(ws + 128 + 2048 * 8);   // 16 KB
    size_t o = 128 + 2048 * 8 + 4096 * 4;
    o = (o + 255) & ~(size_t)255;
    bf16*  xb   = (bf16*) (ws + o); o += (size_t)NTOK * 512 * 2;      //  2 MB
    float* h    = (float*)(ws + o); o += (size_t)TOTROWS * 1024 * 4;  // 16 MB
    bf16*  hb   = (bf16*) (ws + o); o += (size_t)TOTROWS * 1024 * 2;  //  8 MB
    bf16*  tb   = (bf16*) (ws + o); o += (size_t)TOTROWS * 2048 * 2;  // 16 MB
    float* h2   = (float*)(ws + o); o += (size_t)TOTROWS * 1024 * 4;  // 16 MB
    bf16*  orow = (bf16*) (ws + o); o += (size_t)TOTROWS * 512 * 2;   //  4 MB
    // transposed bf16 weights (+144 MB, guarded by ws_size)
    o = (o + 255) & ~(size_t)255;
    bf16* Wint  = (bf16*)(ws + o); o += (size_t)8 * 1024 * 512 * 2;          //  8 MB
    bf16* W1t   = (bf16*)(ws + o); o += (size_t)8 * 2 * 2048 * 1024 * 2;     // 64 MB
    bf16* W2t   = (bf16*)(ws + o); o += (size_t)8 * 2 * 1024 * 2048 * 2;     // 64 MB
    bf16* Woutt = (bf16*)(ws + o); o += (size_t)8 * 512 * 1024 * 2;          //  8 MB
    const bool bt = (o <= ws_size);

    hipMemsetAsync(d_out, 0, (size_t)out_size * sizeof(float), stream);
    hipMemsetAsync(ws, 0, 64, stream);  // counts + cursor

    policy_k<<<NTOK / PTOK, 256, 0, stream>>>(x, pw1, pb1, pg1, pbb1, pw2, pb2, top2, counts);
    prefix_k<<<1, 64, 0, stream>>>(counts, cursor, bases);
    scatter_k<<<NTOK / 256, 256, 0, stream>>>(top2, cursor, list);
    cast_x_k<<<NTOK * 512 / 1024, 256, 0, stream>>>(x, xb);

    if (bt) {
        // transpose-cast all weights to bf16 [N][K]
        wcast_k<<<dim3(128, 8),  256, 0, stream>>>(Win,  Wint,  512,  1024, 8);
        wcast_k<<<dim3(512, 16), 256, 0, stream>>>(W1,   W1t,   1024, 2048, 16);
        wcast_k<<<dim3(512, 16), 256, 0, stream>>>(W2,   W2t,   2048, 1024, 32);
        wcast_k<<<dim3(128, 8),  256, 0, stream>>>(Wout, Woutt, 1024, 512,  16);

        // h (+hb) = gather(x) @ Win_e + b_in    [4096,512]x[512,1024]
        mgemm_k<float, 64, true><<<dim3(8, 32, 8), 256, 0, stream>>>(
            xb, list, nullptr, Wint, (long long)512 * 1024, b_in, 1024, h, hb,
            counts, bases, 512, 1024, 0);

        for (int l = 0; l < 2; ++l) {
            // tb = gelu(hb @ W1_el + b1)        [4096,1024]x[1024,2048]
            mgemm_k<bf16, 128, true><<<dim3(16, 16, 8), 256, 0, stream>>>(
                hb, nullptr, nullptr, W1t + (long long)l * 2048 * 1024,
                (long long)2 * 2048 * 1024, b1 + l * 2048, 2 * 2048, tb, (bf16*)nullptr,
                counts, bases, 1024, 2048, 1);
            // h2 = tb @ W2_el + b2              [4096,2048]x[2048,1024]
            mgemm_k<float, 128, true><<<dim3(8, 16, 8), 256, 0, stream>>>(
                tb, nullptr, nullptr, W2t + (long long)l * 1024 * 2048,
                (long long)2 * 1024 * 2048, b2 + l * 1024, 2 * 1024, h2, (bf16*)nullptr,
                counts, bases, 2048, 1024, 0);
            lngate_k<<<TOTROWS, 256, 0, stream>>>(h, hb, h2, ng, nb, gw, bases, l);
        }

        // orow = hb @ Wout_e + bout             [4096,1024]x[1024,512]
        mgemm_k<bf16, 64, true><<<dim3(4, 32, 8), 256, 0, stream>>>(
            hb, nullptr, nullptr, Woutt, (long long)512 * 1024, bout, 512, orow,
            (bf16*)nullptr, counts, bases, 1024, 512, 0);
    } else {
        // fallback: in-flight fp32->bf16 conversion (R1 configuration)
        mgemm_k<float, 64, false><<<dim3(8, 32, 8), 256, 0, stream>>>(
            xb, list, Win, nullptr, (long long)512 * 1024, b_in, 1024, h, hb,
            counts, bases, 512, 1024, 0);
        for (int l = 0; l < 2; ++l) {
            mgemm_k<bf16, 128, false><<<dim3(16, 16, 8), 256, 0, stream>>>(
                hb, nullptr, W1 + (long long)l * 1024 * 2048, nullptr,
                (long long)2 * 1024 * 2048, b1 + l * 2048, 2 * 2048, tb, (bf16*)nullptr,
                counts, bases, 1024, 2048, 1);
            mgemm_k<float, 128, false><<<dim3(8, 16, 8), 256, 0, stream>>>(
                tb, nullptr, W2 + (long long)l * 2048 * 1024, nullptr,
                (long long)2 * 2048 * 1024, b2 + l * 1024, 2 * 1024, h2, (bf16*)nullptr,
                counts, bases, 2048, 1024, 0);
            lngate_k<<<TOTROWS, 256, 0, stream>>>(h, hb, h2, ng, nb, gw, bases, l);
        }
        mgemm_k<bf16, 64, false><<<dim3(4, 32, 8), 256, 0, stream>>>(
            hb, nullptr, Wout, nullptr, (long long)1024 * 512, bout, 512, orow,
            (bf16*)nullptr, counts, bases, 1024, 512, 0);
    }

    // out[t] += LN(x[t] + orow)
    final_k<<<TOTROWS, 256, 0, stream>>>(x, orow, fng, fnb, bases, list, out);
}

// Round 6
// 804.166 us; speedup vs baseline: 1.1028x; 1.1028x over previous
//
#include <hip/hip_runtime.h>
#include <hip/hip_bf16.h>

#define N_EXP   8
#define NTOK    2048   // B*S
#define TOTROWS 4096   // NTOK * TOP_K
#define PTOK    4      // tokens per policy block

typedef __hip_bfloat16 bf16;
typedef __attribute__((ext_vector_type(8))) short short8;   // 8 bf16 (4 VGPRs)
typedef __attribute__((ext_vector_type(4))) float floatx4;  // MFMA acc

// ---------------- helpers ----------------

__device__ inline float gelu_f(float v) {
    return 0.5f * v * (1.0f + erff(v * 0.70710678118654752440f));
}

// async global->LDS, 16B per lane. LDS dest is wave-uniform base + lane*16.
__device__ __forceinline__ void gll16(const void* g, void* l) {
    __builtin_amdgcn_global_load_lds(
        (__attribute__((address_space(1))) void*)g,
        (__attribute__((address_space(3))) void*)l, 16, 0, 0);
}

__device__ inline float block_sum256(float v, float* red) {
    #pragma unroll
    for (int off = 32; off > 0; off >>= 1)
        v += __shfl_down(v, off, 64);
    __syncthreads();
    if ((threadIdx.x & 63) == 0) red[threadIdx.x >> 6] = v;
    __syncthreads();
    return red[0] + red[1] + red[2] + red[3];
}

__device__ inline unsigned rotl32(unsigned v, int d) { return (v << d) | (v >> (32 - d)); }

// JAX threefry2x32, key = (k0,k1)
__device__ inline void threefry2x32(unsigned k0, unsigned k1, unsigned x0, unsigned x1,
                                    unsigned& o0, unsigned& o1) {
    unsigned ks2 = k0 ^ k1 ^ 0x1BD11BDAu;
    x0 += k0; x1 += k1;
#define TF_R(r) { x0 += x1; x1 = rotl32(x1, r); x1 ^= x0; }
    TF_R(13) TF_R(15) TF_R(26) TF_R(6)
    x0 += k1; x1 += ks2 + 1u;
    TF_R(17) TF_R(29) TF_R(16) TF_R(24)
    x0 += ks2; x1 += k0 + 2u;
    TF_R(13) TF_R(15) TF_R(26) TF_R(6)
    x0 += k0; x1 += k1 + 3u;
    TF_R(17) TF_R(29) TF_R(16) TF_R(24)
    x0 += k1; x1 += ks2 + 4u;
    TF_R(13) TF_R(15) TF_R(26) TF_R(6)
    x0 += ks2; x1 += k0 + 5u;
#undef TF_R
    o0 = x0; o1 = x1;
}

__device__ inline int expert_of(int r, const int* bases) {
    int e = 0;
    #pragma unroll
    for (int i = 1; i < N_EXP; ++i) if (r >= bases[i]) e = i;
    return e;
}

// ---------------- policy + routing ----------------
// 4 tokens/block: pw1 column load reused 4x, 4 independent fma chains.

__global__ __launch_bounds__(256) void policy_k(
    const float* __restrict__ x, const float* __restrict__ pw1,
    const float* __restrict__ pb1, const float* __restrict__ pg1,
    const float* __restrict__ pbb1, const float* __restrict__ pw2,
    const float* __restrict__ pb2, int2* __restrict__ top2, int* __restrict__ counts)
{
    const int tb  = blockIdx.x * PTOK;
    const int lid = threadIdx.x;
    __shared__ float xs[PTOK][512];
    __shared__ float hbs[PTOK][256];
    __shared__ float red[4];
    __shared__ float sc[PTOK][8];

    {
        const float4* xp = (const float4*)(x + (long long)tb * 512);
        float4* xsp = (float4*)&xs[0][0];
        xsp[lid]       = xp[lid];
        xsp[lid + 256] = xp[lid + 256];
    }
    __syncthreads();

    float av[PTOK];
    {
        float b0 = pb1[lid];
        #pragma unroll
        for (int tt = 0; tt < PTOK; ++tt) av[tt] = b0;
    }
    #pragma unroll 4
    for (int d = 0; d < 512; ++d) {
        float w = pw1[d * 256 + lid];
        #pragma unroll
        for (int tt = 0; tt < PTOK; ++tt)
            av[tt] = fmaf(xs[tt][d], w, av[tt]);
    }

    #pragma unroll
    for (int tt = 0; tt < PTOK; ++tt) {
        float s  = block_sum256(av[tt], red);
        float sq = block_sum256(av[tt] * av[tt], red);
        float mean = s * (1.0f / 256.0f);
        float var  = sq * (1.0f / 256.0f) - mean * mean;
        float rstd = rsqrtf(var + 1e-5f);
        float hn = (av[tt] - mean) * rstd * pg1[lid] + pbb1[lid];
        hbs[tt][lid] = gelu_f(hn);
    }
    __syncthreads();

    if (lid < PTOK * 8) {
        const int tt = lid >> 3;
        const int e  = lid & 7;
        float lg = pb2[e];
        for (int j = 0; j < 256; ++j)
            lg = fmaf(hbs[tt][j], pw2[j * 8 + e], lg);
        // jax_threefry_partitionable path: bits = o0 ^ o1 of tf(key, 0, i)
        unsigned idx = (unsigned)(tb + tt) * 8u + (unsigned)e;
        unsigned o0, o1;
        threefry2x32(0u, 42u, 0u, idx, o0, o1);
        unsigned bits = o0 ^ o1;
        float u = __uint_as_float((bits >> 9) | 0x3f800000u) - 1.0f;
        float gml = -logf(-logf(u + 1e-10f) + 1e-10f);
        sc[tt][e] = lg + gml;   // TEMP = 1
    }
    __syncthreads();
    if (lid < PTOK) {
        float b0 = -INFINITY; int i0 = 0;
        #pragma unroll
        for (int e = 0; e < 8; ++e) if (sc[lid][e] > b0) { b0 = sc[lid][e]; i0 = e; }
        float b1v = -INFINITY; int i1 = 0;
        #pragma unroll
        for (int e = 0; e < 8; ++e) if (e != i0 && sc[lid][e] > b1v) { b1v = sc[lid][e]; i1 = e; }
        top2[tb + lid] = make_int2(i0, i1);
        atomicAdd(&counts[i0], 1);
        atomicAdd(&counts[i1], 1);
    }
}

__global__ void prefix_k(const int* __restrict__ counts, int* __restrict__ cursor,
                         int* __restrict__ bases) {
    if (threadIdx.x == 0 && blockIdx.x == 0) {
        int s = 0;
        for (int e = 0; e < N_EXP; ++e) { bases[e] = s; cursor[e] = s; s += counts[e]; }
    }
}

__global__ __launch_bounds__(256) void scatter_k(const int2* __restrict__ top2,
                                                 int* __restrict__ cursor,
                                                 int* __restrict__ list) {
    int t = blockIdx.x * 256 + threadIdx.x;
    int2 p = top2[t];
    int pos = atomicAdd(&cursor[p.x], 1); list[pos] = t;
    pos     = atomicAdd(&cursor[p.y], 1); list[pos] = t;
}

// ---------------- x -> bf16 cast ----------------

__global__ __launch_bounds__(256) void cast_x_k(const float* __restrict__ x,
                                                bf16* __restrict__ xb) {
    int i = (blockIdx.x * 256 + threadIdx.x) * 4;
    float4 v = *(const float4*)(x + i);
    bf16 o[4] = { (bf16)v.x, (bf16)v.y, (bf16)v.z, (bf16)v.w };
    *(unsigned long long*)(xb + i) = *(unsigned long long*)o;
}

// ---------------- weight cast to BLOCKED bf16 tiles ----------------
// in:  [b][K][N] fp32 (row-major, k-major rows)
// out: [b][nt][kt][128][32] bf16, tile = LDS image for mgemm, with the
//      16B-chunk XOR swizzle baked in: content of chunk c is stored at
//      chunk position c ^ ((n'>>1)&3).  (Same XOR is applied on ds_read.)
// Each block: 64k x 64n patch via LDS transpose.

__global__ __launch_bounds__(256) void wcast_k(const float* __restrict__ in,
                                               bf16* __restrict__ outp,
                                               int K, int N, int tiles_k)
{
    const int mt = blockIdx.x;
    const long long b = blockIdx.y;
    const int tk = mt % tiles_k;
    const int tn = mt / tiles_k;
    const int k0 = tk * 64, n0c = tn * 64;
    __shared__ unsigned short t[64 * 80];   // [n_local][k_local], stride 80
    const int tid = threadIdx.x;
    const int rr = tid >> 4;          // k row 0..15 (+16*i)
    const int cc = (tid & 15) * 4;    // n col 0..60
    const float* inb = in + ((long long)b * K + k0) * (long long)N + n0c;
    #pragma unroll
    for (int i = 0; i < 4; ++i) {
        int r = rr + 16 * i;
        float4 v = *(const float4*)(inb + (long long)r * N + cc);
        bf16 x0 = (bf16)v.x, x1 = (bf16)v.y, x2 = (bf16)v.z, x3 = (bf16)v.w;
        t[(cc + 0) * 80 + r] = *(unsigned short*)&x0;
        t[(cc + 1) * 80 + r] = *(unsigned short*)&x1;
        t[(cc + 2) * 80 + r] = *(unsigned short*)&x2;
        t[(cc + 3) * 80 + r] = *(unsigned short*)&x3;
    }
    __syncthreads();
    const int nl = tid >> 2;          // 0..63
    const int ks = (tid & 3) * 16;    // 0,16,32,48
    const int n  = n0c + nl;
    const int nprime = n & 127;
    const int nt = n >> 7;
    const int NT = N >> 7, KT = K >> 5;
    const int swz = (nprime >> 1) & 3;
    #pragma unroll
    for (int u = 0; u < 2; ++u) {
        int k  = k0 + ks + u * 8;
        int kt = k >> 5;
        int ch = (k >> 3) & 3;
        int chs = ch ^ swz;
        long long off = ((((long long)b * NT + nt) * KT + kt) << 12)
                        + (nprime << 5) + (chs << 3);
        *(uint4*)(outp + off) = *(const uint4*)(&t[nl * 80 + ks + u * 8]);
    }
}

// ---------------- MFMA grouped GEMM (async global_load_lds, m97 structure) ----------------
// C[rbase+m][n] = act(A[row][k] * W_e[k][n] + bias_e[n]); A bf16 [M][K],
// W pre-blocked bf16 tiles [e][nt][kt][128][32] (chunk-swizzled).
// Staging: global_load_lds direct to linear LDS (no VGPR round-trip, no
// ds_write). Double-buffered; ONE barrier per K-step; the barrier's implicit
// vmcnt(0) drain completes the prefetched tile.
// Bank swizzle: LDS linear, A's per-lane source chunk and W's stored chunk
// are XOR-permuted by (row>>1)&3; ds_read applies the same XOR -> 2-way max.

template <typename CT, int TMp>
__global__ __launch_bounds__(256) void mgemm_k(
    const bf16* __restrict__ A, const int* __restrict__ gather,
    const bf16* __restrict__ WT, long long westride,
    const float* __restrict__ bias, int bestride,
    CT* __restrict__ C, bf16* __restrict__ Cmir,
    const int* __restrict__ counts, const int* __restrict__ bases,
    int K, int N, int act)
{
    const int e   = blockIdx.z;
    const int cnt = counts[e];
    const int m0  = blockIdx.y * TMp;
    if (m0 >= cnt) return;
    const int rbase = bases[e];
    const int nt  = blockIdx.x;
    const int n0  = nt * 128;
    const int KT  = K >> 5;

    constexpr int MI = TMp / 32;      // per-wave 16-row fragment count
    constexpr int AI = TMp / 64;      // A gload_lds instructions per wave

    __shared__ __align__(16) char As[2][TMp * 64];   // [m][32k] bf16, linear
    __shared__ __align__(16) char Bs[2][128 * 64];   // [n][32k] bf16, linear

    const int tid  = threadIdx.x;
    const int lane = tid & 63;
    const int wv   = tid >> 6;
    const int wm   = (wv & 1) * (TMp / 2);
    const int wn   = (wv >> 1) * 64;
    const int q    = lane >> 4;
    const int ln   = lane & 15;
    const int qsw  = q ^ ((ln >> 1) & 3);   // chunk-XOR read index

    // A source offsets (elements), one per gload instruction; swizzle baked in.
    long long aoff[AI];
    #pragma unroll
    for (int i = 0; i < AI; ++i) {
        int rt = wv * (TMp / 4) + i * 16 + (lane >> 2);   // row in tile
        int r  = m0 + rt; if (r > cnt - 1) r = cnt - 1;
        long long rowp = gather ? (long long)gather[rbase + r] : (long long)(rbase + r);
        int sc = (lane & 3) ^ ((rt >> 1) & 3);
        aoff[i] = rowp * K + sc * 8;
    }
    // B source: blocked contiguous tiles, already swizzled; per-lane 16B.
    const bf16* bsrc = WT + (long long)e * westride + (long long)nt * KT * 4096
                       + wv * 1024 + lane * 8;

    floatx4 acc[MI][4];
    #pragma unroll
    for (int i = 0; i < MI; ++i)
        #pragma unroll
        for (int j = 0; j < 4; ++j)
            acc[i][j] = (floatx4){0.f, 0.f, 0.f, 0.f};

    auto STAGE = [&](int buf, int kt) {
        const int k0 = kt << 5;
        #pragma unroll
        for (int i = 0; i < AI; ++i)
            gll16(A + aoff[i] + k0, &As[buf][wv * (TMp * 16) + i * 1024]);
        const bf16* bs = bsrc + (long long)kt * 4096;
        gll16(bs,       &Bs[buf][wv * 2048]);
        gll16(bs + 512, &Bs[buf][wv * 2048 + 1024]);
    };
    auto COMPUTE = [&](int buf) {
        short8 a_frag[MI], b_frag[4];
        #pragma unroll
        for (int i = 0; i < MI; ++i)
            a_frag[i] = *(const short8*)(&As[buf][(wm + i * 16 + ln) * 64 + qsw * 16]);
        #pragma unroll
        for (int j = 0; j < 4; ++j)
            b_frag[j] = *(const short8*)(&Bs[buf][(wn + j * 16 + ln) * 64 + qsw * 16]);
        #pragma unroll
        for (int i = 0; i < MI; ++i)
            #pragma unroll
            for (int j = 0; j < 4; ++j)
                acc[i][j] = __builtin_amdgcn_mfma_f32_16x16x32_bf16(
                    a_frag[i], b_frag[j], acc[i][j], 0, 0, 0);
    };

    STAGE(0, 0);
    __syncthreads();                 // drains vmcnt -> buf0 ready
    int cur = 0;
    for (int kt = 0; kt < KT - 1; ++kt) {
        STAGE(cur ^ 1, kt + 1);      // async prefetch next tile
        COMPUTE(cur);
        __syncthreads();             // drain: prefetch landed; reads done
        cur ^= 1;
    }
    COMPUTE(cur);

    // epilogue: C/D layout col = lane&15, row = quad*4 + reg
    #pragma unroll
    for (int i = 0; i < MI; ++i) {
        int rbase_i = m0 + wm + i * 16 + q * 4;
        #pragma unroll
        for (int j = 0; j < 4; ++j) {
            int n = n0 + wn + j * 16 + ln;
            float bv = bias[e * bestride + n];
            #pragma unroll
            for (int rg = 0; rg < 4; ++rg) {
                int r = rbase_i + rg;
                if (r >= cnt) continue;
                float v = acc[i][j][rg] + bv;
                if (act) v = gelu_f(v);
                long long off = (long long)(rbase + r) * N + n;
                C[off] = (CT)v;
                if (Cmir) Cmir[off] = (bf16)v;
            }
        }
    }
}

// ---------------- LN + gate + residual (row-global), writes h fp32 + hb bf16 ----------------

__global__ __launch_bounds__(256) void lngate_k(
    float* __restrict__ h, bf16* __restrict__ hb, const float* __restrict__ h2,
    const float* __restrict__ ng, const float* __restrict__ nb,
    const float* __restrict__ gw, const int* __restrict__ bases, int l)
{
    const int r = blockIdx.x;
    const int e = expert_of(r, bases);
    const int lid = threadIdx.x;
    const float* hr  = h  + (long long)r * 1024;
    const float* h2r = h2 + (long long)r * 1024;
    const int off = (e * 2 + l) * 1024;
    __shared__ float red[4];

    float s = 0.f, sq = 0.f, dt = 0.f;
    float hv[4], h2v[4];
    #pragma unroll
    for (int i = 0; i < 4; ++i) {
        int j = lid + 256 * i;
        float a = h2r[j];
        float b = hr[j];
        hv[i] = b; h2v[i] = a;
        s += a; sq += a * a;
        dt = fmaf(b, gw[off + j], dt);
    }
    s  = block_sum256(s, red);
    sq = block_sum256(sq, red);
    dt = block_sum256(dt, red);
    float mean = s * (1.f / 1024.f);
    float rstd = rsqrtf(sq * (1.f / 1024.f) - mean * mean + 1e-5f);
    float gate = 1.f / (1.f + expf(-dt));
    float* hw  = h  + (long long)r * 1024;
    bf16*  hbw = hb + (long long)r * 1024;
    #pragma unroll
    for (int i = 0; i < 4; ++i) {
        int j = lid + 256 * i;
        float v = (h2v[i] - mean) * rstd * ng[off + j] + nb[off + j];
        float nh = hv[i] + gate * v;
        hw[j] = nh;
        hbw[j] = (bf16)nh;
    }
}

// ---------------- final LN(x + out) + combine ----------------

__global__ __launch_bounds__(256) void final_k(
    const float* __restrict__ x, const bf16* __restrict__ orow,
    const float* __restrict__ fng, const float* __restrict__ fnb,
    const int* __restrict__ bases, const int* __restrict__ list,
    float* __restrict__ out)
{
    const int r = blockIdx.x;
    const int e = expert_of(r, bases);
    const int t = list[r];
    const int lid = threadIdx.x;
    __shared__ float red[4];

    float y[2];
    float s = 0.f, sq = 0.f;
    #pragma unroll
    for (int i = 0; i < 2; ++i) {
        int j = lid + 256 * i;
        float v = x[(long long)t * 512 + j] + (float)orow[(long long)r * 512 + j];
        y[i] = v; s += v; sq += v * v;
    }
    s  = block_sum256(s, red);
    sq = block_sum256(sq, red);
    float mean = s * (1.f / 512.f);
    float rstd = rsqrtf(sq * (1.f / 512.f) - mean * mean + 1e-5f);
    #pragma unroll
    for (int i = 0; i < 2; ++i) {
        int j = lid + 256 * i;
        float v = (y[i] - mean) * rstd * fng[e * 512 + j] + fnb[e * 512 + j];
        atomicAdd(&out[(long long)t * 512 + j], v);
    }
}

// ---------------- launch ----------------

extern "C" void kernel_launch(void* const* d_in, const int* in_sizes, int n_in,
                              void* d_out, int out_size, void* d_ws, size_t ws_size,
                              hipStream_t stream) {
    const float* x    = (const float*)d_in[0];
    const float* pw1  = (const float*)d_in[1];
    const float* pb1  = (const float*)d_in[2];
    const float* pg1  = (const float*)d_in[3];
    const float* pbb1 = (const float*)d_in[4];
    const float* pw2  = (const float*)d_in[5];
    const float* pb2  = (const float*)d_in[6];
    const float* Win  = (const float*)d_in[7];
    const float* b_in = (const float*)d_in[8];
    const float* W1   = (const float*)d_in[9];
    const float* b1   = (const float*)d_in[10];
    const float* W2   = (const float*)d_in[11];
    const float* b2   = (const float*)d_in[12];
    const float* ng   = (const float*)d_in[13];
    const float* nb   = (const float*)d_in[14];
    const float* gw   = (const float*)d_in[15];
    const float* Wout = (const float*)d_in[16];
    const float* bout = (const float*)d_in[17];
    const float* fng  = (const float*)d_in[18];
    const float* fnb  = (const float*)d_in[19];
    float* out = (float*)d_out;
    (void)ws_size; (void)in_sizes; (void)n_in;

    char* ws = (char*)d_ws;
    int* counts = (int*)ws;        // 8 ints @ 0
    int* cursor = counts + 8;      // 8 ints @ 32
    int* bases  = cursor + 8;      // 8 ints @ 64
    int2* top2  = (int2*)(ws + 128);             // 16 KB
    int*  list  = (int*)(ws + 128 + 2048 * 8);   // 16 KB
    size_t o = 128 + 2048 * 8 + 4096 * 4;
    o = (o + 255) & ~(size_t)255;
    bf16*  xb   = (bf16*) (ws + o); o += (size_t)NTOK * 512 * 2;      //  2 MB
    float* h    = (float*)(ws + o); o += (size_t)TOTROWS * 1024 * 4;  // 16 MB
    bf16*  hb   = (bf16*) (ws + o); o += (size_t)TOTROWS * 1024 * 2;  //  8 MB
    bf16*  tb   = (bf16*) (ws + o); o += (size_t)TOTROWS * 2048 * 2;  // 16 MB
    float* h2   = (float*)(ws + o); o += (size_t)TOTROWS * 1024 * 4;  // 16 MB
    bf16*  orow = (bf16*) (ws + o); o += (size_t)TOTROWS * 512 * 2;   //  4 MB
    // blocked bf16 weights (+144 MB; fit proven in R4)
    o = (o + 255) & ~(size_t)255;
    bf16* Wint  = (bf16*)(ws + o); o += (size_t)8 * 1024 * 512 * 2;          //  8 MB
    bf16* W1t   = (bf16*)(ws + o); o += (size_t)8 * 2 * 2048 * 1024 * 2;     // 64 MB
    bf16* W2t   = (bf16*)(ws + o); o += (size_t)8 * 2 * 1024 * 2048 * 2;     // 64 MB
    bf16* Woutt = (bf16*)(ws + o); o += (size_t)8 * 512 * 1024 * 2;          //  8 MB

    hipMemsetAsync(d_out, 0, (size_t)out_size * sizeof(float), stream);
    hipMemsetAsync(ws, 0, 64, stream);  // counts + cursor

    policy_k<<<NTOK / PTOK, 256, 0, stream>>>(x, pw1, pb1, pg1, pbb1, pw2, pb2, top2, counts);
    prefix_k<<<1, 64, 0, stream>>>(counts, cursor, bases);
    scatter_k<<<NTOK / 256, 256, 0, stream>>>(top2, cursor, list);
    cast_x_k<<<NTOK * 512 / 1024, 256, 0, stream>>>(x, xb);

    // blocked+swizzled bf16 weight tiles: grid.x = tiles_k * tiles_n
    wcast_k<<<dim3(8 * 16,  8),  256, 0, stream>>>(Win,  Wint,  512,  1024, 8);
    wcast_k<<<dim3(16 * 32, 16), 256, 0, stream>>>(W1,   W1t,   1024, 2048, 16);
    wcast_k<<<dim3(32 * 16, 16), 256, 0, stream>>>(W2,   W2t,   2048, 1024, 32);
    wcast_k<<<dim3(16 * 8,  8),  256, 0, stream>>>(Wout, Woutt, 1024, 512,  16);

    // h (+hb) = gather(x) @ Win_e + b_in    [4096,512]x[512,1024]
    mgemm_k<float, 64><<<dim3(8, 32, 8), 256, 0, stream>>>(
        xb, list, Wint, (long long)512 * 1024, b_in, 1024, h, hb,
        counts, bases, 512, 1024, 0);

    for (int l = 0; l < 2; ++l) {
        // tb = gelu(hb @ W1_el + b1)        [4096,1024]x[1024,2048]
        mgemm_k<bf16, 128><<<dim3(16, 16, 8), 256, 0, stream>>>(
            hb, nullptr, W1t + (long long)l * 2048 * 1024,
            (long long)2 * 2048 * 1024, b1 + l * 2048, 2 * 2048, tb, (bf16*)nullptr,
            counts, bases, 1024, 2048, 1);
        // h2 = tb @ W2_el + b2              [4096,2048]x[2048,1024]
        mgemm_k<float, 128><<<dim3(8, 16, 8), 256, 0, stream>>>(
            tb, nullptr, W2t + (long long)l * 1024 * 2048,
            (long long)2 * 1024 * 2048, b2 + l * 1024, 2 * 1024, h2, (bf16*)nullptr,
            counts, bases, 2048, 1024, 0);
        // h += sigmoid(h . gw) * LN(h2); hb mirror
        lngate_k<<<TOTROWS, 256, 0, stream>>>(h, hb, h2, ng, nb, gw, bases, l);
    }

    // orow = hb @ Wout_e + bout             [4096,1024]x[1024,512]
    mgemm_k<bf16, 64><<<dim3(4, 32, 8), 256, 0, stream>>>(
        hb, nullptr, Woutt, (long long)512 * 1024, bout, 512, orow, (bf16*)nullptr,
        counts, bases, 1024, 512, 0);

    // out[t] += LN(x[t] + orow)
    final_k<<<TOTROWS, 256, 0, stream>>>(x, orow, fng, fnb, bases, list, out);
}